// Round 1
// baseline (459.105 us; speedup 1.0000x reference)
//
#include <hip/hip_runtime.h>
#include <hip/hip_bf16.h>

#define N_NODES 50000
#define N_EDGES 800000
#define N_BUCKETS 64
#define M_PAD 50048
#define SCAN_NB 196  // ceil(50000 / 256)

typedef short short8 __attribute__((ext_vector_type(8)));
typedef float floatx4 __attribute__((ext_vector_type(4)));
typedef float floatx2 __attribute__((ext_vector_type(2)));

// ---- bf16 helpers (RNE) ---------------------------------------------------
__device__ __forceinline__ unsigned short f2bf(float f) {
    unsigned u = __float_as_uint(f);
    unsigned r = (u + 0x7fff + ((u >> 16) & 1)) >> 16;
    return (unsigned short)r;
}
__device__ __forceinline__ float bf2f(unsigned short h) {
    return __uint_as_float(((unsigned)h) << 16);
}
__device__ __forceinline__ void expand2(unsigned u, float& lo, float& hi) {
    lo = __uint_as_float(u << 16);
    hi = __uint_as_float(u & 0xffff0000u);
}

// ---- fp8 e4m3 (OCP) HW conversion helpers ---------------------------------
__device__ __forceinline__ unsigned pack4_fp8(float f0, float f1, float f2, float f3) {
    int v = __builtin_amdgcn_cvt_pk_fp8_f32(f0, f1, 0, false);
    v = __builtin_amdgcn_cvt_pk_fp8_f32(f2, f3, v, true);
    return (unsigned)v;
}
__device__ __forceinline__ void accum_fp8x4(float* a, unsigned u, float w) {
    floatx2 lo = __builtin_amdgcn_cvt_pk_f32_fp8((int)u, false);
    floatx2 hi = __builtin_amdgcn_cvt_pk_f32_fp8((int)u, true);
    a[0] += lo[0] * w; a[1] += lo[1] * w;
    a[2] += hi[0] * w; a[3] += hi[1] * w;
}
__device__ __forceinline__ void accum16(float* a, uint4 u, float w) {
    accum_fp8x4(a + 0,  u.x, w);
    accum_fp8x4(a + 4,  u.y, w);
    accum_fp8x4(a + 8,  u.z, w);
    accum_fp8x4(a + 12, u.w, w);
}
__device__ __forceinline__ void accum8(float* a, uint2 u, float w) {
    accum_fp8x4(a + 0, u.x, w);
    accum_fp8x4(a + 4, u.y, w);
}

// async global->LDS, 16B per lane
__device__ __forceinline__ void gload16(const void* gp, void* lp) {
    __builtin_amdgcn_global_load_lds(
        (const __attribute__((address_space(1))) unsigned int*)gp,
        (__attribute__((address_space(3))) unsigned int*)lp,
        16, 0, 0);
}

// ---------------------------------------------------------------------------
__global__ void k_init(int* __restrict__ cnt, float* __restrict__ gb) {
    int i = blockIdx.x * blockDim.x + threadIdx.x;
    if (i < N_NODES) cnt[i] = 0;
    if (i < N_BUCKETS * 256) gb[i] = 0.0f;
}

__global__ void k_count(const int* __restrict__ col, int* __restrict__ cnt) {
    int e = blockIdx.x * blockDim.x + threadIdx.x;
    if (e < N_EDGES) atomicAdd(&cnt[col[e]], 1);
}

// --- 3-phase hierarchical exclusive scan of PADDED capacities --------------
// cap[i] = (cnt[i]+1 self-loop) rounded up to a multiple of 4: every CSR
// segment starts 32B-aligned and has length%4==0, so the aggregation kernel
// can consume edges 4-at-a-time per gather instruction with no masking.
__global__ __launch_bounds__(256) void k_scanA(const int* __restrict__ cnt,
                                               int* __restrict__ bsum) {
    __shared__ int red[256];
    int t = threadIdx.x;
    int i = blockIdx.x * 256 + t;
    red[t] = (i < N_NODES) ? ((cnt[i] + 4) & ~3) : 0;
    __syncthreads();
    for (int d = 128; d > 0; d >>= 1) {
        if (t < d) red[t] += red[t + d];
        __syncthreads();
    }
    if (t == 0) bsum[blockIdx.x] = red[0];
}

__global__ __launch_bounds__(256) void k_scanB(const int* __restrict__ bsum,
                                               int* __restrict__ bbase,
                                               int* __restrict__ off) {
    __shared__ int sc[256];
    int t = threadIdx.x;
    sc[t] = (t < SCAN_NB) ? bsum[t] : 0;
    __syncthreads();
    for (int d = 1; d < 256; d <<= 1) {
        int v = 0;
        if (t >= d) v = sc[t - d];
        __syncthreads();
        if (t >= d) sc[t] += v;
        __syncthreads();
    }
    if (t < SCAN_NB) bbase[t] = sc[t] - bsum[t];
    if (t == SCAN_NB - 1) off[N_NODES] = sc[t];   // padded total
}

__global__ __launch_bounds__(256) void k_scanC(const int* __restrict__ cnt,
                                               const int* __restrict__ bbase,
                                               int* __restrict__ off,
                                               int* __restrict__ cursor,
                                               float* __restrict__ dinv,
                                               int2* __restrict__ epack) {
    __shared__ int sc[256];
    int t = threadIdx.x;
    int i = blockIdx.x * 256 + t;
    int c = (i < N_NODES) ? cnt[i] : 0;
    int cap = (c + 4) & ~3;          // + self-loop, pad to multiple of 4
    sc[t] = cap;
    __syncthreads();
    for (int d = 1; d < 256; d <<= 1) {
        int v = 0;
        if (t >= d) v = sc[t - d];
        __syncthreads();
        if (t >= d) sc[t] += v;
        __syncthreads();
    }
    if (i < N_NODES) {
        int excl = sc[t] - cap + bbase[blockIdx.x];
        off[i] = excl;
        cursor[i] = excl;
        float di = 1.0f / sqrtf((float)(c + 1));
        dinv[i] = di;
        epack[excl + c] = make_int2(i, __float_as_int(di));  // self-loop edge
        for (int p = c + 1; p < cap; ++p)
            epack[excl + p] = make_int2(i, 0);               // pad edge, w=0
    }
}

__global__ void k_fill(const int* __restrict__ row, const int* __restrict__ col,
                       const float* __restrict__ dinv, int* __restrict__ cursor,
                       int2* __restrict__ epack) {
    int e = blockIdx.x * blockDim.x + threadIdx.x;
    if (e >= N_EDGES) return;
    int v = col[e];
    int p = atomicAdd(&cursor[v], 1);
    int r = row[e];
    epack[p] = make_int2(r, __float_as_int(dinv[r]));
}

// W [K][N] fp32 -> transposed split bf16 WT{h,l} [N][K] (weights stay exact)
__global__ void k_prepW(const float* __restrict__ W,
                        unsigned short* __restrict__ Th,
                        unsigned short* __restrict__ Tl, int K, int N) {
    int idx = blockIdx.x * blockDim.x + threadIdx.x;
    if (idx >= K * N) return;
    int n = idx / K, k = idx - n * K;
    float v = W[(size_t)k * N + n];
    unsigned short h = f2bf(v);
    Th[idx] = h;
    Tl[idx] = f2bf(v - bf2f(h));
}

// x fp32 -> fp8 e4m3; one thread per 4 features
__global__ void k_prepX8(const float* __restrict__ x, unsigned char* __restrict__ xq) {
    int i = blockIdx.x * blockDim.x + threadIdx.x;
    if (i >= N_NODES * 32) return;
    const float* s = x + (size_t)i * 4;
    *(unsigned*)&xq[(size_t)i * 4] = pack4_fp8(s[0], s[1], s[2], s[3]);
}

// ---------------------------------------------------------------------------
// Wave-per-node aggregation over fp8-e4m3 rows, fp32 accum.
// MLP-maximized layout: lane = (edge-slot g = lane>>4, feature-slot q = lane&15).
// One gather instruction covers FOUR edges (16 lanes x DIM/16 bytes each), so
// a main-loop iteration keeps 16 edges (4 gathers + 2 descriptor int4 loads)
// in flight per wave -- 4x the in-flight edge count of the previous version,
// attacking the latency-bound regime the counters showed (VALUBusy 20%,
// HBM 13%, MfmaUtil 0). Self-loop + w=0 pads live in the edge list (cap%4==0).
// Epilogue: shfl_xor(16/32) cross-group reduce, per-lane g-selected slice out.
// POOL=0: bf16 row out (feeds GEMM). POOL=1: bias+relu+bucketed mean-pool.
template <int DIM, int POOL>
__global__ __launch_bounds__(256) void k_aggf(
    const unsigned char* __restrict__ xq, const int* __restrict__ off,
    const int2* __restrict__ epack, const float* __restrict__ dinv,
    const float* __restrict__ bias, unsigned short* __restrict__ outb,
    float* __restrict__ gb) {
    const int F = DIM / 16;       // fp8 bytes (features) per lane: 16 or 8
    __shared__ float gpart[256];
    if constexpr (POOL) {
        gpart[threadIdx.x] = 0.0f;
        __syncthreads();
    }
    const int wv = threadIdx.x >> 6;
    const int li = threadIdx.x & 63;
    const int g = li >> 4;        // edge slot within a gather instruction
    const int q = li & 15;        // feature-chunk slot
    const int v = blockIdx.x * 4 + wv;   // grid divides N exactly
    const float dv = dinv[v];
    const unsigned char* __restrict__ xf = xq + q * F;
    float acc[F];
#pragma unroll
    for (int i = 0; i < F; ++i) acc[i] = 0.0f;

    int j = off[v];
    const int e = off[v + 1];     // 4-aligned start, length % 4 == 0
    // main loop: 16 edges in flight (2 desc int4 + 4 row gathers)
    for (; j + 16 <= e; j += 16) {
        const int2* ep = epack + j + g * 4;
        int4 dA = *(const int4*)ep;        // edges g*4+0, g*4+1
        int4 dB = *(const int4*)(ep + 2);  // edges g*4+2, g*4+3
        if constexpr (DIM == 256) {
            uint4 g0 = *(const uint4*)&xf[(size_t)dA.x * DIM];
            uint4 g1 = *(const uint4*)&xf[(size_t)dA.z * DIM];
            uint4 g2 = *(const uint4*)&xf[(size_t)dB.x * DIM];
            uint4 g3 = *(const uint4*)&xf[(size_t)dB.z * DIM];
            accum16(acc, g0, __int_as_float(dA.y));
            accum16(acc, g1, __int_as_float(dA.w));
            accum16(acc, g2, __int_as_float(dB.y));
            accum16(acc, g3, __int_as_float(dB.w));
        } else {
            uint2 g0 = *(const uint2*)&xf[(size_t)dA.x * DIM];
            uint2 g1 = *(const uint2*)&xf[(size_t)dA.z * DIM];
            uint2 g2 = *(const uint2*)&xf[(size_t)dB.x * DIM];
            uint2 g3 = *(const uint2*)&xf[(size_t)dB.z * DIM];
            accum8(acc, g0, __int_as_float(dA.y));
            accum8(acc, g1, __int_as_float(dA.w));
            accum8(acc, g2, __int_as_float(dB.y));
            accum8(acc, g3, __int_as_float(dB.w));
        }
    }
    // tail: 4 edges per step (cap is a multiple of 4)
    for (; j < e; j += 4) {
        int2 d = epack[j + g];
        if constexpr (DIM == 256) {
            uint4 g0 = *(const uint4*)&xf[(size_t)d.x * DIM];
            accum16(acc, g0, __int_as_float(d.y));
        } else {
            uint2 g0 = *(const uint2*)&xf[(size_t)d.x * DIM];
            accum8(acc, g0, __int_as_float(d.y));
        }
    }

    // cross-group reduce (lanes l, l^16, l^32, l^48 hold the same features)
#pragma unroll
    for (int i = 0; i < F; ++i) {
        float t = acc[i];
        t += __shfl_xor(t, 16);
        t += __shfl_xor(t, 32);
        acc[i] = t * dv;
    }

    if constexpr (!POOL) {
        if constexpr (DIM == 256) {
            // lane writes features q*16 + g*4 .. +3 (compile-time selects)
            float o0 = g == 0 ? acc[0] : g == 1 ? acc[4] : g == 2 ? acc[8]  : acc[12];
            float o1 = g == 0 ? acc[1] : g == 1 ? acc[5] : g == 2 ? acc[9]  : acc[13];
            float o2 = g == 0 ? acc[2] : g == 1 ? acc[6] : g == 2 ? acc[10] : acc[14];
            float o3 = g == 0 ? acc[3] : g == 1 ? acc[7] : g == 2 ? acc[11] : acc[15];
            uint2 o;
            o.x = (unsigned)f2bf(o0) | ((unsigned)f2bf(o1) << 16);
            o.y = (unsigned)f2bf(o2) | ((unsigned)f2bf(o3) << 16);
            *(uint2*)&outb[(size_t)v * DIM + q * 16 + g * 4] = o;
        } else {
            float o0 = g == 0 ? acc[0] : g == 1 ? acc[2] : g == 2 ? acc[4] : acc[6];
            float o1 = g == 0 ? acc[1] : g == 1 ? acc[3] : g == 2 ? acc[5] : acc[7];
            unsigned o = (unsigned)f2bf(o0) | ((unsigned)f2bf(o1) << 16);
            *(unsigned*)&outb[(size_t)v * DIM + q * 8 + g * 2] = o;
        }
    } else {
        // DIM == 256 only
        float o0 = g == 0 ? acc[0] : g == 1 ? acc[4] : g == 2 ? acc[8]  : acc[12];
        float o1 = g == 0 ? acc[1] : g == 1 ? acc[5] : g == 2 ? acc[9]  : acc[13];
        float o2 = g == 0 ? acc[2] : g == 1 ? acc[6] : g == 2 ? acc[10] : acc[14];
        float o3 = g == 0 ? acc[3] : g == 1 ? acc[7] : g == 2 ? acc[11] : acc[15];
        const int fb = q * 16 + g * 4;
        floatx4 bv = *(const floatx4*)&bias[fb];
        atomicAdd(&gpart[fb + 0], fmaxf(o0 + bv[0], 0.0f));
        atomicAdd(&gpart[fb + 1], fmaxf(o1 + bv[1], 0.0f));
        atomicAdd(&gpart[fb + 2], fmaxf(o2 + bv[2], 0.0f));
        atomicAdd(&gpart[fb + 3], fmaxf(o3 + bv[3], 0.0f));
        __syncthreads();
        atomicAdd(&gb[(blockIdx.x & (N_BUCKETS - 1)) * 256 + threadIdx.x],
                  gpart[threadIdx.x]);
    }
}

// ---------------------------------------------------------------------------
// bf16-A x split-bf16-B MFMA GEMM: C = A @ (Bh+Bl) (+bias)(relu)
// B pre-transposed [N][K]. 128x128 tile, BK=32, SINGLE-buffered LDS (32KB ->
// 5 blocks/CU; explicit dbuf was occupancy-limited at 48KB and cross-block
// implicit overlap is the better latency-hiding mechanism). LDS-staged
// coalesced epilogue (reuses all 32KB). OUTFP8=1: fp8-e4m3 writeback.
template <int BIAS, int RELU, int OUTFP8>
__global__ __launch_bounds__(256) void k_gemm_b(
    const unsigned short* __restrict__ A,
    const unsigned short* __restrict__ Bh, const unsigned short* __restrict__ Bl,
    const float* __restrict__ bias, void* __restrict__ Cout,
    int M, int K, int N) {
    __shared__ unsigned short smem[4 * 4096];   // 32KB
    unsigned short* As  = smem;                 // 8KB
    unsigned short* BsH = smem + 4096;          // 8KB
    unsigned short* BsL = smem + 8192;          // 8KB
    int tid = threadIdx.x;
    int lane = tid & 63;
    int w = tid >> 6;
    int wr = w & 1, wc = w >> 1;
    int bm = blockIdx.x * 128, bn = blockIdx.y * 128;

    floatx4 acc[4][4];
    floatx4 zero = {0.f, 0.f, 0.f, 0.f};
#pragma unroll
    for (int t = 0; t < 4; ++t)
#pragma unroll
        for (int u = 0; u < 4; ++u) acc[t][u] = zero;

    int c0 = w * 2, c1 = c0 + 1;
    int srow = lane >> 2;
    int kg = ((lane & 3) - ((lane >> 3) & 3)) & 3;
    int kc = kg * 8;
    const unsigned short* Ap0 = A + (size_t)(bm + c0 * 16 + srow) * K + kc;
    const unsigned short* Ap1 = A + (size_t)(bm + c1 * 16 + srow) * K + kc;
    const unsigned short* Bh0 = Bh + (size_t)(bn + c0 * 16 + srow) * K + kc;
    const unsigned short* Bh1 = Bh + (size_t)(bn + c1 * 16 + srow) * K + kc;
    const unsigned short* Bl0 = Bl + (size_t)(bn + c0 * 16 + srow) * K + kc;
    const unsigned short* Bl1 = Bl + (size_t)(bn + c1 * 16 + srow) * K + kc;

    const int KT = K >> 5;
    int fr = lane & 15;
    int fq = lane >> 4;
    int cl = ((fq + (fr >> 1)) & 3) * 8;

    for (int kt = 0; kt < KT; ++kt) {
        int k0 = kt * 32;
        gload16(Ap0 + k0, As + c0 * 512);
        gload16(Ap1 + k0, As + c1 * 512);
        gload16(Bh0 + k0, BsH + c0 * 512);
        gload16(Bh1 + k0, BsH + c1 * 512);
        gload16(Bl0 + k0, BsL + c0 * 512);
        gload16(Bl1 + k0, BsL + c1 * 512);
        __syncthreads();
        short8 av[4], bhv[4], blv[4];
#pragma unroll
        for (int t = 0; t < 4; ++t) {
            av[t]  = *(const short8*)&As[(wr * 64 + t * 16 + fr) * 32 + cl];
            bhv[t] = *(const short8*)&BsH[(wc * 64 + t * 16 + fr) * 32 + cl];
            blv[t] = *(const short8*)&BsL[(wc * 64 + t * 16 + fr) * 32 + cl];
        }
#pragma unroll
        for (int t = 0; t < 4; ++t)
#pragma unroll
            for (int u = 0; u < 4; ++u) {
                acc[t][u] = __builtin_amdgcn_mfma_f32_16x16x32_bf16(av[t], bhv[u], acc[t][u], 0, 0, 0);
                acc[t][u] = __builtin_amdgcn_mfma_f32_16x16x32_bf16(av[t], blv[u], acc[t][u], 0, 0, 0);
            }
        __syncthreads();
    }

    // ---- LDS-staged epilogue (reuses all 32KB) ----
    unsigned short* cq = smem + w * 4096;
#pragma unroll
    for (int u = 0; u < 4; ++u) {
        int colq = u * 16 + fr;
        float bv = BIAS ? bias[bn + wc * 64 + colq] : 0.0f;
#pragma unroll
        for (int t = 0; t < 4; ++t) {
#pragma unroll
            for (int r = 0; r < 4; ++r) {
                float o = acc[t][u][r] + bv;
                if (RELU) o = fmaxf(o, 0.f);
                cq[(t * 16 + fq * 4 + r) * 64 + colq] = f2bf(o);
            }
        }
    }
    __syncthreads();
    int lr = tid >> 4;
    int lc = (tid & 15) * 8;
    int wcq = lc >> 6;
    int lcq = lc & 63;
#pragma unroll
    for (int i = 0; i < 8; ++i) {
        int rowt = i * 16 + lr;
        int wrq = rowt >> 6;
        const unsigned short* src =
            smem + (wrq + wcq * 2) * 4096 + (rowt & 63) * 64 + lcq;
        int rowg = bm + rowt;
        if (rowg < M) {
            if (!OUTFP8) {
                unsigned short* C = (unsigned short*)Cout;
                *(uint4*)&C[(size_t)rowg * N + bn + lc] = *(const uint4*)src;
            } else {
                uint4 b = *(const uint4*)src;
                float f0, f1, f2, f3, f4, f5, f6, f7;
                expand2(b.x, f0, f1); expand2(b.y, f2, f3);
                expand2(b.z, f4, f5); expand2(b.w, f6, f7);
                uint2 q;
                q.x = pack4_fp8(f0, f1, f2, f3);
                q.y = pack4_fp8(f4, f5, f6, f7);
                unsigned char* C8 = (unsigned char*)Cout;
                *(uint2*)&C8[(size_t)rowg * N + bn + lc] = q;
            }
        }
    }
}

// tiny MLP; first reduces the 64 pool buckets
__global__ void k_mlp(const float* __restrict__ gb,
                      const float* __restrict__ Wf1, const float* __restrict__ bf1,
                      const float* __restrict__ Wf2, const float* __restrict__ bf2,
                      const float* __restrict__ Wf3, const float* __restrict__ bf3,
                      float* __restrict__ out) {
    __shared__ float s0[256], s1[128], s2[64];
    int t = threadIdx.x;
    float sum = 0.0f;
    for (int b = 0; b < N_BUCKETS; ++b) sum += gb[b * 256 + t];
    s0[t] = sum * (1.0f / (float)N_NODES);
    __syncthreads();
    if (t < 128) {
        float a = bf1[t];
        for (int k = 0; k < 256; ++k) a += s0[k] * Wf1[k * 128 + t];
        s1[t] = fmaxf(a, 0.0f);
    }
    __syncthreads();
    if (t < 64) {
        float a = bf2[t];
        for (int k = 0; k < 128; ++k) a += s1[k] * Wf2[k * 64 + t];
        s2[t] = fmaxf(a, 0.0f);
    }
    __syncthreads();
    if (t == 0) {
        float a = bf3[0];
        for (int k = 0; k < 64; ++k) a += s2[k] * Wf3[k];
        out[0] = a;
    }
}

extern "C" void kernel_launch(void* const* d_in, const int* in_sizes, int n_in,
                              void* d_out, int out_size, void* d_ws, size_t ws_size,
                              hipStream_t stream) {
    const float* x  = (const float*)d_in[0];
    const int* ei   = (const int*)d_in[1];
    const float* W1 = (const float*)d_in[2];
    const float* b1 = (const float*)d_in[3];
    const float* W2 = (const float*)d_in[4];
    const float* b2 = (const float*)d_in[5];
    const float* W3 = (const float*)d_in[6];
    const float* b3 = (const float*)d_in[7];
    const float* Wf1 = (const float*)d_in[8];
    const float* bf1 = (const float*)d_in[9];
    const float* Wf2 = (const float*)d_in[10];
    const float* bf2 = (const float*)d_in[11];
    const float* Wf3 = (const float*)d_in[12];
    const float* bf3 = (const float*)d_in[13];
    float* out = (float*)d_out;

    char* p = (char*)d_ws;
    auto alloc = [&](size_t bytes) {
        void* r = (void*)p;
        p += (bytes + 255) & ~((size_t)255);
        return r;
    };
    int*   cnt    = (int*)  alloc(N_NODES * sizeof(int));
    int*   off    = (int*)  alloc((N_NODES + 1) * sizeof(int));
    int*   cursor = (int*)  alloc(N_NODES * sizeof(int));
    int*   bsum   = (int*)  alloc(SCAN_NB * sizeof(int));
    int*   bbase  = (int*)  alloc(SCAN_NB * sizeof(int));
    float* dinv   = (float*)alloc(N_NODES * sizeof(float));
    int2*  epack  = (int2*) alloc((size_t)(N_EDGES + 4 * N_NODES) * sizeof(int2)); // + self/pad slots
    float* gb     = (float*)alloc(N_BUCKETS * 256 * sizeof(float));
    unsigned short* W1h = (unsigned short*)alloc(128 * 256 * 2);
    unsigned short* W1l = (unsigned short*)alloc(128 * 256 * 2);
    unsigned short* W2h = (unsigned short*)alloc(256 * 512 * 2);
    unsigned short* W2l = (unsigned short*)alloc(256 * 512 * 2);
    unsigned short* W3h = (unsigned short*)alloc(512 * 256 * 2);
    unsigned short* W3l = (unsigned short*)alloc(512 * 256 * 2);
    unsigned char*  xq  = (unsigned char*) alloc((size_t)N_NODES * 128);
    unsigned short* t0  = (unsigned short*)alloc((size_t)M_PAD * 128 * 2);
    unsigned char*  h1q = (unsigned char*) alloc((size_t)N_NODES * 256);
    unsigned short* t1  = (unsigned short*)alloc((size_t)M_PAD * 256 * 2);
    unsigned short* h2  = (unsigned short*)alloc((size_t)M_PAD * 512 * 2);
    unsigned char*  t2q = (unsigned char*) alloc((size_t)N_NODES * 256);

    const int* row = ei;
    const int* col = ei + N_EDGES;

    const int NB = (N_NODES + 255) / 256;
    const int EB = (N_EDGES + 255) / 256;

    // CSR build + norm (hierarchical scan over 4-padded capacities incl. self)
    k_init<<<NB, 256, 0, stream>>>(cnt, gb);
    k_count<<<EB, 256, 0, stream>>>(col, cnt);
    k_scanA<<<SCAN_NB, 256, 0, stream>>>(cnt, bsum);
    k_scanB<<<1, 256, 0, stream>>>(bsum, bbase, off);
    k_scanC<<<SCAN_NB, 256, 0, stream>>>(cnt, bbase, off, cursor, dinv, epack);
    k_fill<<<EB, 256, 0, stream>>>(row, col, dinv, cursor, epack);

    // weight prep (transpose + exact split) and x -> fp8
    k_prepW<<<(128 * 256 + 255) / 256, 256, 0, stream>>>(W1, W1h, W1l, 128, 256);
    k_prepW<<<(256 * 512 + 255) / 256, 256, 0, stream>>>(W2, W2h, W2l, 256, 512);
    k_prepW<<<(512 * 256 + 255) / 256, 256, 0, stream>>>(W3, W3h, W3l, 512, 256);
    k_prepX8<<<(N_NODES * 32 + 255) / 256, 256, 0, stream>>>(x, xq);

    const int M = N_NODES;
    const int MB = (M + 127) / 128; // 391

    // conv1: t0 = agg(x_fp8) -> bf16; h1 = relu(t0@W1 + b1) -> fp8
    k_aggf<128, 0><<<N_NODES / 4, 256, 0, stream>>>(
        xq, off, epack, dinv, nullptr, t0, nullptr);
    {
        dim3 grid(MB, 256 / 128);
        k_gemm_b<1, 1, 1><<<grid, 256, 0, stream>>>(t0, W1h, W1l, b1, h1q, M, 128, 256);
    }
    // conv2: t1 = agg(h1_fp8) -> bf16; h2 = relu(t1@W2 + b2) -> bf16
    k_aggf<256, 0><<<N_NODES / 4, 256, 0, stream>>>(
        h1q, off, epack, dinv, nullptr, t1, nullptr);
    {
        dim3 grid(MB, 512 / 128);
        k_gemm_b<1, 1, 0><<<grid, 256, 0, stream>>>(t1, W2h, W2l, b2, h2, M, 256, 512);
    }
    // conv3: t2 = h2@W3 -> fp8; fused agg + bias + relu + bucketed mean-pool
    {
        dim3 grid(MB, 256 / 128);
        k_gemm_b<0, 0, 1><<<grid, 256, 0, stream>>>(h2, W3h, W3l, nullptr, t2q, M, 512, 256);
    }
    k_aggf<256, 1><<<N_NODES / 4, 256, 0, stream>>>(
        t2q, off, epack, dinv, b3, nullptr, gb);

    // MLP (reduces buckets internally)
    k_mlp<<<1, 256, 0, stream>>>(gb, Wf1, bf1, Wf2, bf2, Wf3, bf3, out);
}